// Round 4
// baseline (112.825 us; speedup 1.0000x reference)
//
#include <hip/hip_runtime.h>

// DendralNeuron: out[b,d] = min( min_f(x[b,f]-Wmin[d,f]), min_f(Wmax[d,f]-x[b,f]) )
// R4 theory: kernel is LDS-PIPE-bound, not VALU-bound (R3: packing subs was
// neutral; occupancy bump was neutral). 4x2 tile had 8 DS : 64 VALU wave-instrs
// per f-quad -> DS pipe (1/CU, shared by 4 SIMDs) 2-3x oversubscribed.
// Fix: 8x4 register tile (BM=128, BN=64) -> 16 DS : 256 VALU -> parity.
// l1-pass / mx-pass split keeps nv/wv live ranges disjoint (VGPR control).
// F split 12 ways (ZSPLIT) -> 768 blocks = 3/CU; atomic-min combine.

constexpr int F_DIM = 784;
constexpr int BM = 128;
constexpr int BN = 64;
constexpr int BK = 16;
constexpr int LSTR = BK + 4;          // 20 floats: 16B-aligned rows, 2-way banks max
constexpr int NCHUNK = F_DIM / BK;    // 49
constexpr int ZSPLIT = 12;            // slices of 4 or 5 chunks

typedef float f4v __attribute__((ext_vector_type(4)));
typedef float f2v __attribute__((ext_vector_type(2)));

__global__ __launch_bounds__(256, 4)
void dendral_init_kernel(float* __restrict__ out) {
  const int i = blockIdx.x * 256 + threadIdx.x;
  const float inf = __builtin_inff();
  f4v v = {inf, inf, inf, inf};
  ((f4v*)out)[i] = v;
}

__device__ inline void atomic_min_float(float* addr, float v) {
  if (v >= 0.0f) atomicMin((int*)addr, __float_as_int(v));
  else           atomicMax((unsigned int*)addr, __float_as_uint(v));
}

__global__ __launch_bounds__(256, 3)
void dendral_min_kernel(const float* __restrict__ x,
                        const float* __restrict__ wmin,
                        const float* __restrict__ wmax,
                        float* __restrict__ out, int D) {
  __shared__ float lx[BM * LSTR];     // x tile  [128][20] = 10 KB
  __shared__ float lwn[BN * LSTR];    // wmin    [64][20]  =  5 KB
  __shared__ float lwx[BN * LSTR];    // wmax    [64][20]  =  5 KB

  const int t  = threadIdx.x;
  const int tx = t & 15;              // d-cols: tx + 16*{0..3}
  const int ty = t >> 4;              // b-rows: ty + 16*{0..7}
  const int b0 = blockIdx.x * BM;
  const int d0 = blockIdx.y * BN;
  const int c0 = (blockIdx.z * NCHUNK) / ZSPLIT;
  const int c1 = ((blockIdx.z + 1) * NCHUNK) / ZSPLIT;

  // Staging: x tile 128x16 = 512 float4 -> 2/thread; W tiles 64x16 each ->
  // 1 float4 of wmin + 1 of wmax per thread.
  const int xr = t >> 1;              // 0..127
  const int xc = (t & 1) << 3;        // 0 or 8 (two float4: xc, xc+4)
  const int wr = t >> 2;              // 0..63
  const int wc = (t & 3) << 2;        // 0,4,8,12

  const float* xg = x + (size_t)(b0 + xr) * F_DIM + xc;
  const float* ng = wmin + (size_t)(d0 + wr) * F_DIM + wc;
  const float* wg = wmax + (size_t)(d0 + wr) * F_DIM + wc;
  float* sx = lx + xr * LSTR + xc;    // 16B-aligned (20*4=80B rows, xc*4 in {0,32})
  float* sn = lwn + wr * LSTR + wc;
  float* sw = lwx + wr * LSTR + wc;

  // Prefetch first chunk of this z-slice into registers.
  f4v pxa = *(const f4v*)(xg + c0 * BK);
  f4v pxb = *(const f4v*)(xg + c0 * BK + 4);
  f4v pn  = *(const f4v*)(ng + c0 * BK);
  f4v pw  = *(const f4v*)(wg + c0 * BK);

  float l1[8][4], mx[8][4];
#pragma unroll
  for (int r = 0; r < 8; ++r)
#pragma unroll
    for (int c = 0; c < 4; ++c) {
      l1[r][c] = __builtin_inff();
      mx[r][c] = -__builtin_inff();
    }

  for (int kc = c0; kc < c1; ++kc) {
    *(f4v*)sx       = pxa;
    *(f4v*)(sx + 4) = pxb;
    *(f4v*)sn       = pn;
    *(f4v*)sw       = pw;
    __syncthreads();
    if (kc + 1 < c1) {                // register prefetch of next chunk
      pxa = *(const f4v*)(xg + (kc + 1) * BK);
      pxb = *(const f4v*)(xg + (kc + 1) * BK + 4);
      pn  = *(const f4v*)(ng + (kc + 1) * BK);
      pw  = *(const f4v*)(wg + (kc + 1) * BK);
    }
#pragma unroll
    for (int f = 0; f < BK; f += 4) {
      f4v xv[8];
#pragma unroll
      for (int r = 0; r < 8; ++r)     // 4 distinct addrs/wave -> broadcast
        xv[r] = *(const f4v*)&lx[(ty + 16 * r) * LSTR + f];

      {                               // L1 pass: min_f(x - wmin)
        f4v nv[4];
#pragma unroll
        for (int c = 0; c < 4; ++c)
          nv[c] = *(const f4v*)&lwn[(tx + 16 * c) * LSTR + f];
#pragma unroll
        for (int r = 0; r < 8; ++r)
#pragma unroll
          for (int c = 0; c < 4; ++c) {
            f2v a_lo = xv[r].xy - nv[c].xy;   // v_pk_add_f32 (neg)
            f2v a_hi = xv[r].zw - nv[c].zw;
            l1[r][c] = fminf(l1[r][c], fminf(a_lo.x, a_lo.y));  // v_min3
            l1[r][c] = fminf(l1[r][c], fminf(a_hi.x, a_hi.y));
          }
      }
      {                               // L2 pass: min_f(wmax-x) == -max_f(x-wmax)
        f4v wv[4];
#pragma unroll
        for (int c = 0; c < 4; ++c)
          wv[c] = *(const f4v*)&lwx[(tx + 16 * c) * LSTR + f];
#pragma unroll
        for (int r = 0; r < 8; ++r)
#pragma unroll
          for (int c = 0; c < 4; ++c) {
            f2v u_lo = xv[r].xy - wv[c].xy;
            f2v u_hi = xv[r].zw - wv[c].zw;
            mx[r][c] = fmaxf(mx[r][c], fmaxf(u_lo.x, u_lo.y));  // v_max3
            mx[r][c] = fmaxf(mx[r][c], fmaxf(u_hi.x, u_hi.y));
          }
      }
    }
    __syncthreads();
  }

  // Combine this z-slice's partial into out via device-scope atomic min.
#pragma unroll
  for (int r = 0; r < 8; ++r)
#pragma unroll
    for (int c = 0; c < 4; ++c) {
      const int b = b0 + ty + 16 * r;
      const int d = d0 + tx + 16 * c;
      atomic_min_float(&out[(size_t)b * D + d], fminf(l1[r][c], -mx[r][c]));
    }
}

extern "C" void kernel_launch(void* const* d_in, const int* in_sizes, int n_in,
                              void* d_out, int out_size, void* d_ws, size_t ws_size,
                              hipStream_t stream) {
  const float* x    = (const float*)d_in[0];
  const float* wmin = (const float*)d_in[1];
  const float* wmax = (const float*)d_in[2];
  float* out = (float*)d_out;
  const int B = in_sizes[0] / F_DIM;  // 1024
  const int D = in_sizes[1] / F_DIM;  // 512

  dendral_init_kernel<<<out_size / (256 * 4), 256, 0, stream>>>(out);

  dim3 grid(B / BM, D / BN, ZSPLIT); // 8 x 8 x 12 = 768 blocks -> 3 per CU
  dendral_min_kernel<<<grid, 256, 0, stream>>>(x, wmin, wmax, out, D);
  (void)n_in; (void)d_ws; (void)ws_size;
}